// Round 1
// baseline (45.997 us; speedup 1.0000x reference)
//
#include <hip/hip_runtime.h>

#define B_ 4
#define N_ 256
#define D_ 256
#define L_ 256
#define H_ 128
// PAIR_DIM = 2*D + 3 + L = 771
#define NB_ 4   // rows per block in precompute kernel (reuses W1 stream 4x)

// ---------------------------------------------------------------------------
// Kernel 0: canonicalize object_mask into int[B*N] in workspace.
// The harness may pass bool as 1-byte or as int32; detect by byte pattern:
// under int32 layout, bytes at offset %4 != 0 (within first B*N bytes) are all
// zero (values are 0/1); under byte layout they are random 0/1.
// ---------------------------------------------------------------------------
__global__ void mask_canon_kernel(const unsigned char* __restrict__ mraw,
                                  int* __restrict__ mout) {
    __shared__ int isByteLayout;
    if (threadIdx.x == 0) isByteLayout = 0;
    __syncthreads();
    const int n = B_ * N_;
    for (int p = threadIdx.x; p < n; p += blockDim.x) {
        if ((p & 3) != 0 && mraw[p] != 0) isByteLayout = 1;
    }
    __syncthreads();
    if (isByteLayout) {
        for (int i = threadIdx.x; i < n; i += blockDim.x)
            mout[i] = (mraw[i] != 0) ? 1 : 0;
    } else {
        const int* mi = (const int*)mraw;
        for (int i = threadIdx.x; i < n; i += blockDim.x)
            mout[i] = (mi[i] != 0) ? 1 : 0;
    }
}

// ---------------------------------------------------------------------------
// Kernel A: per-row precompute.
//   A[b,n,h]  = s_i[b,n,h] + cproj[b,n,h]
//   Bt[b,h,n] = s_j[b,n,h] - cproj[b,n,h] + s_lang[b,h] + b1[h]
// One block = NB_ consecutive rows of one batch, 128 threads (one per h).
// ---------------------------------------------------------------------------
__global__ __launch_bounds__(H_) void precompute_kernel(
    const float* __restrict__ feat,     // (B,N,D)
    const float* __restrict__ lang,     // (B,L)
    const float* __restrict__ centers,  // (B,N,3)
    const float* __restrict__ W1,       // (771,H)
    const float* __restrict__ b1,       // (H)
    float* __restrict__ Aout,           // (B,N,H)
    float* __restrict__ Bt)             // (B,H,N)
{
    __shared__ float fs[NB_][D_];
    __shared__ float ls[L_];
    __shared__ float cs[NB_][3];

    const int blocksPerBatch = N_ / NB_;               // 64
    const int b  = blockIdx.x / blocksPerBatch;
    const int n0 = (blockIdx.x % blocksPerBatch) * NB_;
    const int t  = threadIdx.x;                        // 0..127 (= h)

    for (int i = t; i < NB_ * D_; i += H_) {
        int r = i >> 8, d = i & (D_ - 1);
        fs[r][d] = feat[((b * N_) + (n0 + r)) * D_ + d];
    }
    for (int i = t; i < L_; i += H_) ls[i] = lang[b * L_ + i];
    if (t < NB_ * 3) {
        int r = t / 3, c = t % 3;
        cs[r][c] = centers[((b * N_) + (n0 + r)) * 3 + c] * 0.2f;  // /5
    }
    __syncthreads();

    const int h = t;
    float si[NB_] = {0.f, 0.f, 0.f, 0.f};
    float sj[NB_] = {0.f, 0.f, 0.f, 0.f};
    float sl = 0.f;
    const float* __restrict__ Wi = W1 + h;                    // rows 0..D-1
    const float* __restrict__ Wj = W1 + D_ * H_ + h;          // rows D..2D-1
    const float* __restrict__ Wl = W1 + (2 * D_ + 3) * H_ + h;// rows 2D+3..

    // D_ == L_ == 256, so one loop streams all three W1 panels.
    for (int d = 0; d < D_; ++d) {
        float wi = Wi[d * H_];
        float wj = Wj[d * H_];
        float wl = Wl[d * H_];
        sl += ls[d] * wl;
#pragma unroll
        for (int r = 0; r < NB_; ++r) {
            si[r] += fs[r][d] * wi;
            sj[r] += fs[r][d] * wj;
        }
    }

    const float wr0 = W1[(2 * D_ + 0) * H_ + h];
    const float wr1 = W1[(2 * D_ + 1) * H_ + h];
    const float wr2 = W1[(2 * D_ + 2) * H_ + h];
    const float bb  = b1[h];

#pragma unroll
    for (int r = 0; r < NB_; ++r) {
        float srel = cs[r][0] * wr0 + cs[r][1] * wr1 + cs[r][2] * wr2;
        int n = n0 + r;
        Aout[((b * N_) + n) * H_ + h] = si[r] + srel;
        Bt[((b * H_) + h) * N_ + n]   = sj[r] - srel + sl + bb;
    }
}

// ---------------------------------------------------------------------------
// Kernel B: one block per (b,n). 256 threads.
//   thread j: score[j] = sum_h relu(A[b,n,h] + Bt[b,h,j]) * W2[h] + b2
//   mask -> -1e9, block softmax over j, write weights,
//   thread d: ctx[d] = sum_j w[j]*feat[b,j,d]; enhanced = feat[b,n,d]+ctx.
// ---------------------------------------------------------------------------
__global__ __launch_bounds__(N_) void pair_kernel(
    const float* __restrict__ feat,   // (B,N,D)
    const float* __restrict__ Aout,   // (B,N,H)
    const float* __restrict__ Bt,     // (B,H,N)
    const float* __restrict__ W2,     // (H)
    const float* __restrict__ b2,     // (1)
    const int*   __restrict__ mask,   // (B,N) canonical
    float* __restrict__ outEnh,       // (B,N,D)
    float* __restrict__ outW)         // (B,N,N)
{
    const int b = blockIdx.x / N_;
    const int n = blockIdx.x % N_;
    const int j = threadIdx.x;

    __shared__ float As[H_];
    __shared__ float W2s[H_];
    __shared__ float wsh[N_];
    __shared__ float red[4];

    if (j < H_) {
        As[j]  = Aout[((b * N_) + n) * H_ + j];
        W2s[j] = W2[j];
    }
    __syncthreads();

    const float* __restrict__ btp = Bt + (size_t)(b * H_) * N_ + j;
    float acc = 0.f;
#pragma unroll 4
    for (int h = 0; h < H_; ++h) {
        float v = As[h] + btp[h * N_];
        acc += fmaxf(v, 0.f) * W2s[h];
    }
    float score = acc + b2[0];
    const bool valid = (mask[b * N_ + n] != 0) && (mask[b * N_ + j] != 0);
    if (!valid) score = -1e9f;

    // block softmax over 256 threads (4 waves of 64)
    float m = score;
    for (int off = 32; off >= 1; off >>= 1) m = fmaxf(m, __shfl_xor(m, off));
    const int wid = j >> 6;
    if ((j & 63) == 0) red[wid] = m;
    __syncthreads();
    m = fmaxf(fmaxf(red[0], red[1]), fmaxf(red[2], red[3]));

    float e = __expf(score - m);
    float s = e;
    for (int off = 32; off >= 1; off >>= 1) s += __shfl_xor(s, off);
    __syncthreads();               // red reuse hazard
    if ((j & 63) == 0) red[wid] = s;
    __syncthreads();
    s = red[0] + red[1] + red[2] + red[3];

    const float w = e / s;
    wsh[j] = w;
    outW[(((size_t)(b * N_) + n) * N_) + j] = w;
    __syncthreads();

    // relation context: thread j = output dim d (N_ == D_ == 256)
    const float* __restrict__ fb = feat + (size_t)b * N_ * D_;
    float ctx = 0.f;
#pragma unroll 4
    for (int jj = 0; jj < N_; ++jj) ctx += wsh[jj] * fb[jj * D_ + j];
    outEnh[((b * N_) + n) * D_ + j] = fb[n * D_ + j] + ctx;
}

// ---------------------------------------------------------------------------
extern "C" void kernel_launch(void* const* d_in, const int* in_sizes, int n_in,
                              void* d_out, int out_size, void* d_ws, size_t ws_size,
                              hipStream_t stream) {
    const float* feat    = (const float*)d_in[0];  // (B,N,D)
    const float* lang    = (const float*)d_in[1];  // (B,L)
    const float* centers = (const float*)d_in[2];  // (B,N,3)
    const unsigned char* mraw = (const unsigned char*)d_in[3];  // (B,N) bool/int
    const float* W1      = (const float*)d_in[4];  // (771,H)
    const float* b1      = (const float*)d_in[5];  // (H)
    const float* W2      = (const float*)d_in[6];  // (H,1)
    const float* b2      = (const float*)d_in[7];  // (1)

    float* outEnh = (float*)d_out;                       // (B,N,D)
    float* outW   = (float*)d_out + (size_t)B_ * N_ * D_; // (B,N,N)

    float* Aout = (float*)d_ws;                          // B*N*H floats
    float* Bt   = Aout + (size_t)B_ * N_ * H_;           // B*H*N floats
    int*   mi   = (int*)(Bt + (size_t)B_ * H_ * N_);     // B*N ints

    mask_canon_kernel<<<1, 256, 0, stream>>>(mraw, mi);
    precompute_kernel<<<B_ * N_ / NB_, H_, 0, stream>>>(feat, lang, centers, W1,
                                                        b1, Aout, Bt);
    pair_kernel<<<B_ * N_, N_, 0, stream>>>(feat, Aout, Bt, W2, b2, mi,
                                            outEnh, outW);
}

// Round 2
// 34.081 us; speedup vs baseline: 1.3497x; 1.3497x over previous
//
#include <hip/hip_runtime.h>

#define B_ 4
#define N_ 256
#define D_ 256
#define L_ 256
#define H_ 128
// PAIR_DIM = 2*D + 3 + L = 771
#define NB_ 4                 // rows per block in precompute (W1 reuse x4)
#define QT_ 4                 // d-range split into 4 quarter-groups
#define TPB_PRE (H_ * QT_)    // 512 threads

// ---------------------------------------------------------------------------
// Kernel A: per-row precompute.
//   A[b,n,h]  = s_i[b,n,h] + cproj[b,n,h]
//   Bt[b,h,n] = s_j[b,n,h] - cproj[b,n,h] + s_lang[b,h] + b1[h]
// 512 threads: t = q*128 + h. Quarter-group q accumulates d in [q*64,(q+1)*64)
// with 8-wide register prefetch; LDS reduce across q.
// ---------------------------------------------------------------------------
__global__ __launch_bounds__(TPB_PRE) void precompute_kernel(
    const float* __restrict__ feat,     // (B,N,D)
    const float* __restrict__ lang,     // (B,L)
    const float* __restrict__ centers,  // (B,N,3)
    const float* __restrict__ W1,       // (771,H)
    const float* __restrict__ b1,       // (H)
    float* __restrict__ Aout,           // (B,N,H)
    float* __restrict__ Bt)             // (B,H,N)
{
    __shared__ float fs[NB_][D_];              // 4 KB
    __shared__ float ls[L_];                   // 1 KB
    __shared__ float cs[NB_][3];
    __shared__ float red[QT_][2 * NB_ + 1][H_];// 18.4 KB

    const int blocksPerBatch = N_ / NB_;       // 64
    const int b  = blockIdx.x / blocksPerBatch;
    const int n0 = (blockIdx.x % blocksPerBatch) * NB_;
    const int t  = threadIdx.x;
    const int q  = t >> 7;                     // 0..3
    const int h  = t & (H_ - 1);               // 0..127

    for (int i = t; i < NB_ * D_; i += TPB_PRE) {
        int r = i >> 8, d = i & (D_ - 1);
        fs[r][d] = feat[((b * N_) + (n0 + r)) * D_ + d];
    }
    for (int i = t; i < L_; i += TPB_PRE) ls[i] = lang[b * L_ + i];
    if (t < NB_ * 3) {
        int r = t / 3, c = t % 3;
        cs[r][c] = centers[((b * N_) + (n0 + r)) * 3 + c] * 0.2f;  // /5
    }
    __syncthreads();

    float si[NB_] = {0.f, 0.f, 0.f, 0.f};
    float sj[NB_] = {0.f, 0.f, 0.f, 0.f};
    float sl = 0.f;
    const float* __restrict__ Wi = W1 + h;                      // rows 0..D-1
    const float* __restrict__ Wj = W1 + D_ * H_ + h;            // rows D..2D-1
    const float* __restrict__ Wl = W1 + (2 * D_ + 3) * H_ + h;  // rows 2D+3..

    const int d0 = q * (D_ / QT_);             // 64-wide quarter
    for (int dd = d0; dd < d0 + D_ / QT_; dd += 8) {
        float wi[8], wj[8], wl[8];
#pragma unroll
        for (int k = 0; k < 8; ++k) {          // issue all 24 loads first
            wi[k] = Wi[(dd + k) * H_];
            wj[k] = Wj[(dd + k) * H_];
            wl[k] = Wl[(dd + k) * H_];
        }
#pragma unroll
        for (int k = 0; k < 8; ++k) {
            int d = dd + k;
            sl += ls[d] * wl[k];
#pragma unroll
            for (int r = 0; r < NB_; ++r) {
                si[r] += fs[r][d] * wi[k];
                sj[r] += fs[r][d] * wj[k];
            }
        }
    }

#pragma unroll
    for (int r = 0; r < NB_; ++r) {
        red[q][r][h]       = si[r];
        red[q][NB_ + r][h] = sj[r];
    }
    red[q][2 * NB_][h] = sl;
    __syncthreads();

    if (t < H_) {                              // h == t
        float sit[NB_] = {0.f, 0.f, 0.f, 0.f};
        float sjt[NB_] = {0.f, 0.f, 0.f, 0.f};
        float slt = 0.f;
#pragma unroll
        for (int qq = 0; qq < QT_; ++qq) {
#pragma unroll
            for (int r = 0; r < NB_; ++r) {
                sit[r] += red[qq][r][t];
                sjt[r] += red[qq][NB_ + r][t];
            }
            slt += red[qq][2 * NB_][t];
        }
        const float wr0 = W1[(2 * D_ + 0) * H_ + t];
        const float wr1 = W1[(2 * D_ + 1) * H_ + t];
        const float wr2 = W1[(2 * D_ + 2) * H_ + t];
        const float bb  = b1[t];
#pragma unroll
        for (int r = 0; r < NB_; ++r) {
            float srel = cs[r][0] * wr0 + cs[r][1] * wr1 + cs[r][2] * wr2;
            int n = n0 + r;
            Aout[((b * N_) + n) * H_ + t] = sit[r] + srel;
            Bt[((b * H_) + t) * N_ + n]   = sjt[r] - srel + slt + bb;
        }
    }
}

// ---------------------------------------------------------------------------
// Kernel B: one block per (b,n). 256 threads. Mask layout sniff inlined.
// ---------------------------------------------------------------------------
__global__ __launch_bounds__(N_) void pair_kernel(
    const float* __restrict__ feat,   // (B,N,D)
    const float* __restrict__ Aout,   // (B,N,H)
    const float* __restrict__ Bt,     // (B,H,N)
    const float* __restrict__ W2,     // (H)
    const float* __restrict__ b2,     // (1)
    const unsigned char* __restrict__ mraw,  // (B,N) bool-as-byte or int32
    float* __restrict__ outEnh,       // (B,N,D)
    float* __restrict__ outW)         // (B,N,N)
{
    const int b = blockIdx.x / N_;
    const int n = blockIdx.x % N_;
    const int j = threadIdx.x;

    __shared__ float As[H_];
    __shared__ float W2s[H_];
    __shared__ float wsh[N_];
    __shared__ float red[4];
    __shared__ int   layoutByte;

    if (j == 0) layoutByte = 0;
    if (j < H_) {
        As[j]  = Aout[((b * N_) + n) * H_ + j];
        W2s[j] = W2[j];
    }
    __syncthreads();

    // layout sniff: int32 layout => all bytes at offset%4!=0 are zero
    {
        uchar4 v = ((const uchar4*)mraw)[j];   // 256 threads cover B_*N_ bytes
        if (v.y | v.z | v.w) layoutByte = 1;   // benign same-value race
    }
    __syncthreads();

    bool valid;
    if (layoutByte) {
        valid = (mraw[b * N_ + n] != 0) && (mraw[b * N_ + j] != 0);
    } else {
        const int* mi = (const int*)mraw;
        valid = (mi[b * N_ + n] != 0) && (mi[b * N_ + j] != 0);
    }

    const float* __restrict__ btp = Bt + (size_t)(b * H_) * N_ + j;
    float acc = 0.f;
#pragma unroll 4
    for (int h = 0; h < H_; ++h) {
        float v = As[h] + btp[h * N_];
        acc += fmaxf(v, 0.f) * W2s[h];
    }
    float score = acc + b2[0];
    if (!valid) score = -1e9f;

    // block softmax over 256 threads (4 waves of 64)
    float m = score;
    for (int off = 32; off >= 1; off >>= 1) m = fmaxf(m, __shfl_xor(m, off));
    const int wid = j >> 6;
    if ((j & 63) == 0) red[wid] = m;
    __syncthreads();
    m = fmaxf(fmaxf(red[0], red[1]), fmaxf(red[2], red[3]));

    float e = __expf(score - m);
    float s = e;
    for (int off = 32; off >= 1; off >>= 1) s += __shfl_xor(s, off);
    __syncthreads();               // red reuse hazard
    if ((j & 63) == 0) red[wid] = s;
    __syncthreads();
    s = red[0] + red[1] + red[2] + red[3];

    const float w = e / s;
    wsh[j] = w;
    outW[(((size_t)(b * N_) + n) * N_) + j] = w;
    __syncthreads();

    // relation context: thread j = output dim d (N_ == D_ == 256)
    const float* __restrict__ fb = feat + (size_t)b * N_ * D_;
    float ctx = 0.f;
#pragma unroll 4
    for (int jj = 0; jj < N_; ++jj) ctx += wsh[jj] * fb[jj * D_ + j];
    outEnh[((b * N_) + n) * D_ + j] = fb[n * D_ + j] + ctx;
}

// ---------------------------------------------------------------------------
extern "C" void kernel_launch(void* const* d_in, const int* in_sizes, int n_in,
                              void* d_out, int out_size, void* d_ws, size_t ws_size,
                              hipStream_t stream) {
    const float* feat    = (const float*)d_in[0];  // (B,N,D)
    const float* lang    = (const float*)d_in[1];  // (B,L)
    const float* centers = (const float*)d_in[2];  // (B,N,3)
    const unsigned char* mraw = (const unsigned char*)d_in[3];  // (B,N)
    const float* W1      = (const float*)d_in[4];  // (771,H)
    const float* b1      = (const float*)d_in[5];  // (H)
    const float* W2      = (const float*)d_in[6];  // (H,1)
    const float* b2      = (const float*)d_in[7];  // (1)

    float* outEnh = (float*)d_out;                        // (B,N,D)
    float* outW   = (float*)d_out + (size_t)B_ * N_ * D_; // (B,N,N)

    float* Aout = (float*)d_ws;                           // B*N*H floats
    float* Bt   = Aout + (size_t)B_ * N_ * H_;            // B*H*N floats

    precompute_kernel<<<B_ * N_ / NB_, TPB_PRE, 0, stream>>>(feat, lang, centers,
                                                             W1, b1, Aout, Bt);
    pair_kernel<<<B_ * N_, N_, 0, stream>>>(feat, Aout, Bt, W2, b2, mraw,
                                            outEnh, outW);
}

// Round 3
// 23.008 us; speedup vs baseline: 1.9992x; 1.4813x over previous
//
#include <hip/hip_runtime.h>

#define B_ 4
#define N_ 256
#define D_ 256
#define L_ 256
#define H_ 128
// PAIR_DIM = 2*D + 3 + L = 771; W1 rows: [0,256)=Wi, [256,512)=Wj,
// [512,515)=Wrel, [515,771)=Wlang
#define NB_ 4     // n-rows per block (both kernels)
#define G_  8     // d-groups in precompute
#define TPB_ 1024

// ---------------------------------------------------------------------------
// Kernel A: per-row precompute.
//   A[b,n,h]  = s_i + cproj           (B,N,H)
//   Bt[b,h,n] = s_j - cproj + s_lang + b1   (B,H,N)
// 1024 threads: t = g*128 + h; group g covers d in [g*32,(g+1)*32).
// ---------------------------------------------------------------------------
__global__ __launch_bounds__(TPB_) void precompute_kernel(
    const float* __restrict__ feat,     // (B,N,D)
    const float* __restrict__ lang,     // (B,L)
    const float* __restrict__ centers,  // (B,N,3)
    const float* __restrict__ W1,       // (771,H)
    const float* __restrict__ b1,       // (H)
    float* __restrict__ Aout,           // (B,N,H)
    float* __restrict__ Bt)             // (B,H,N)
{
    __shared__ float fs[NB_][D_];                 // 4 KB
    __shared__ float ls[L_];                      // 1 KB
    __shared__ float cs[NB_][3];
    __shared__ float red[G_][2 * NB_ + 1][H_];    // 36.9 KB

    const int blocksPerBatch = N_ / NB_;          // 64
    const int b  = blockIdx.x / blocksPerBatch;
    const int n0 = (blockIdx.x % blocksPerBatch) * NB_;
    const int t  = threadIdx.x;
    const int g  = t >> 7;                        // 0..7
    const int h  = t & (H_ - 1);                  // 0..127

    {   // exactly NB_*D_ = 1024 elements, one per thread
        int r = t >> 8, d = t & (D_ - 1);
        fs[r][d] = feat[((b * N_) + (n0 + r)) * D_ + d];
    }
    if (t < L_) ls[t] = lang[b * L_ + t];
    if (t < NB_ * 3) {
        int r = t / 3, c = t % 3;
        cs[r][c] = centers[((b * N_) + (n0 + r)) * 3 + c] * 0.2f;  // /5
    }
    __syncthreads();

    float si[NB_] = {0.f, 0.f, 0.f, 0.f};
    float sj[NB_] = {0.f, 0.f, 0.f, 0.f};
    float sl = 0.f;
    const float* __restrict__ Wi = W1 + h;                      // rows 0..255
    const float* __restrict__ Wj = W1 + D_ * H_ + h;            // rows 256..511
    const float* __restrict__ Wl = W1 + (2 * D_ + 3) * H_ + h;  // rows 515..770

    const int d0 = g * (D_ / G_);                 // 32-wide slice
    for (int dd = d0; dd < d0 + D_ / G_; dd += 8) {
        float wi[8], wj[8], wl[8];
#pragma unroll
        for (int k = 0; k < 8; ++k) {             // issue all 24 loads first
            wi[k] = Wi[(dd + k) * H_];
            wj[k] = Wj[(dd + k) * H_];
            wl[k] = Wl[(dd + k) * H_];
        }
#pragma unroll
        for (int k = 0; k < 8; ++k) {
            int d = dd + k;
            sl += ls[d] * wl[k];
#pragma unroll
            for (int r = 0; r < NB_; ++r) {
                si[r] += fs[r][d] * wi[k];
                sj[r] += fs[r][d] * wj[k];
            }
        }
    }

#pragma unroll
    for (int r = 0; r < NB_; ++r) {
        red[g][r][h]        = si[r];
        red[g][NB_ + r][h]  = sj[r];
    }
    red[g][2 * NB_][h] = sl;
    __syncthreads();

    if (t < H_) {                                 // h == t
        float sit[NB_] = {0.f, 0.f, 0.f, 0.f};
        float sjt[NB_] = {0.f, 0.f, 0.f, 0.f};
        float slt = 0.f;
#pragma unroll
        for (int gg = 0; gg < G_; ++gg) {
#pragma unroll
            for (int r = 0; r < NB_; ++r) {
                sit[r] += red[gg][r][t];
                sjt[r] += red[gg][NB_ + r][t];
            }
            slt += red[gg][2 * NB_][t];
        }
        const float wr0 = W1[(2 * D_ + 0) * H_ + t];
        const float wr1 = W1[(2 * D_ + 1) * H_ + t];
        const float wr2 = W1[(2 * D_ + 2) * H_ + t];
        const float bb  = b1[t];
#pragma unroll
        for (int r = 0; r < NB_; ++r) {
            float srel = cs[r][0] * wr0 + cs[r][1] * wr1 + cs[r][2] * wr2;
            int n = n0 + r;
            Aout[((b * N_) + n) * H_ + t] = sit[r] + srel;
            Bt[((b * H_) + t) * N_ + n]   = sjt[r] - srel + slt + bb;
        }
    }
}

// ---------------------------------------------------------------------------
// Kernel B: one block per (b, 4-row n-tile). 1024 threads: t = q*256 + j.
// Quarter q covers h in [q*32,(q+1)*32) for scores, jj in [q*64,(q+1)*64)
// for context. Bt panel (128 KB) + feat[b] (256 KB) amortized over 4 rows.
// ---------------------------------------------------------------------------
__global__ __launch_bounds__(TPB_) void pair_kernel(
    const float* __restrict__ feat,   // (B,N,D)
    const float* __restrict__ Aout,   // (B,N,H)
    const float* __restrict__ Bt,     // (B,H,N)
    const float* __restrict__ W2,     // (H)
    const float* __restrict__ b2,     // (1)
    const unsigned char* __restrict__ mraw,  // (B,N) bool-as-byte or int32
    float* __restrict__ outEnh,       // (B,N,D)
    float* __restrict__ outW)         // (B,N,N)
{
    __shared__ float As[NB_][H_];          // 2 KB
    __shared__ float W2s[H_];              // 0.5 KB
    __shared__ float part[4][NB_][N_];     // 16 KB
    __shared__ float wsh[NB_][N_];         // 4 KB
    __shared__ unsigned char msk[N_];
    __shared__ int layoutByte;

    const int tiles = N_ / NB_;            // 64
    const int b  = blockIdx.x / tiles;
    const int n0 = (blockIdx.x % tiles) * NB_;
    const int t  = threadIdx.x;
    const int q  = t >> 8;                 // 0..3
    const int j  = t & (N_ - 1);           // 0..255

    if (t == 0) layoutByte = 0;
    __syncthreads();

    // layout sniff: under int32 layout all bytes at offset%4!=0 are zero
    if (t < 256) {
        uchar4 v = ((const uchar4*)mraw)[t];   // covers B_*N_ bytes
        if (v.y | v.z | v.w) layoutByte = 1;   // benign same-value race
    }
    if (t < NB_ * H_) {                        // 512 threads: As rows
        int r = t >> 7, h = t & (H_ - 1);
        As[r][h] = Aout[((b * N_) + (n0 + r)) * H_ + h];
    } else if (t < NB_ * H_ + H_) {
        W2s[t - NB_ * H_] = W2[t - NB_ * H_];
    }
    __syncthreads();

    if (t < N_) {
        msk[t] = layoutByte ? (mraw[b * N_ + t] != 0)
                            : (((const int*)mraw)[b * N_ + t] != 0);
    }
    const float b2v = b2[0];
    __syncthreads();

    // ---- scores: quarter q covers 32 h-rows of the Bt panel ----
    {
        const float* __restrict__ btp =
            Bt + ((size_t)(b * H_) + q * 32) * N_ + j;
        float acc[NB_] = {0.f, 0.f, 0.f, 0.f};
#pragma unroll 8
        for (int hh = 0; hh < 32; ++hh) {
            float bt = btp[hh * N_];
            float w2 = W2s[q * 32 + hh];
#pragma unroll
            for (int r = 0; r < NB_; ++r)
                acc[r] += fmaxf(As[r][q * 32 + hh] + bt, 0.f) * w2;
        }
#pragma unroll
        for (int r = 0; r < NB_; ++r) part[q][r][j] = acc[r];
    }
    __syncthreads();

    // ---- softmax: wave r (of 16) handles row r ----
    {
        const int wid = t >> 6, lane = t & 63;
        if (wid < NB_) {
            const int r = wid;
            float sc[4], mx = -1e30f;
#pragma unroll
            for (int k = 0; k < 4; ++k) {
                int jj = lane + k * 64;
                float s = part[0][r][jj] + part[1][r][jj] +
                          part[2][r][jj] + part[3][r][jj] + b2v;
                if (!(msk[n0 + r] && msk[jj])) s = -1e9f;
                sc[k] = s;
                mx = fmaxf(mx, s);
            }
            for (int off = 32; off >= 1; off >>= 1)
                mx = fmaxf(mx, __shfl_xor(mx, off));
            float e[4], sm = 0.f;
#pragma unroll
            for (int k = 0; k < 4; ++k) { e[k] = __expf(sc[k] - mx); sm += e[k]; }
            for (int off = 32; off >= 1; off >>= 1) sm += __shfl_xor(sm, off);
            const float inv = 1.f / sm;
#pragma unroll
            for (int k = 0; k < 4; ++k) {
                int jj = lane + k * 64;
                float w = e[k] * inv;
                wsh[r][jj] = w;
                outW[(((size_t)(b * N_) + (n0 + r)) * N_) + jj] = w;
            }
        }
    }
    __syncthreads();

    // ---- context: quarter q covers 64 jj-rows of feat[b] ----
    {
        const float* __restrict__ fb = feat + (size_t)b * N_ * D_;
        const int d = j;
        float facc[NB_] = {0.f, 0.f, 0.f, 0.f};
#pragma unroll 8
        for (int jj = q * 64; jj < q * 64 + 64; ++jj) {
            float f = fb[jj * D_ + d];
#pragma unroll
            for (int r = 0; r < NB_; ++r) facc[r] += wsh[r][jj] * f;
        }
#pragma unroll
        for (int r = 0; r < NB_; ++r) part[q][r][d] = facc[r];
    }
    __syncthreads();

    if (t < N_) {
        const float* __restrict__ fb = feat + (size_t)b * N_ * D_;
        const int d = t;
#pragma unroll
        for (int r = 0; r < NB_; ++r) {
            float v = part[0][r][d] + part[1][r][d] +
                      part[2][r][d] + part[3][r][d] + fb[(n0 + r) * D_ + d];
            outEnh[((b * N_) + (n0 + r)) * D_ + d] = v;
        }
    }
}

// ---------------------------------------------------------------------------
extern "C" void kernel_launch(void* const* d_in, const int* in_sizes, int n_in,
                              void* d_out, int out_size, void* d_ws, size_t ws_size,
                              hipStream_t stream) {
    const float* feat    = (const float*)d_in[0];  // (B,N,D)
    const float* lang    = (const float*)d_in[1];  // (B,L)
    const float* centers = (const float*)d_in[2];  // (B,N,3)
    const unsigned char* mraw = (const unsigned char*)d_in[3];  // (B,N)
    const float* W1      = (const float*)d_in[4];  // (771,H)
    const float* b1      = (const float*)d_in[5];  // (H)
    const float* W2      = (const float*)d_in[6];  // (H,1)
    const float* b2      = (const float*)d_in[7];  // (1)

    float* outEnh = (float*)d_out;                        // (B,N,D)
    float* outW   = (float*)d_out + (size_t)B_ * N_ * D_; // (B,N,N)

    float* Aout = (float*)d_ws;                           // B*N*H floats
    float* Bt   = Aout + (size_t)B_ * N_ * H_;            // B*H*N floats

    precompute_kernel<<<B_ * N_ / NB_, TPB_, 0, stream>>>(feat, lang, centers,
                                                          W1, b1, Aout, Bt);
    pair_kernel<<<B_ * N_ / NB_, TPB_, 0, stream>>>(feat, Aout, Bt, W2, b2,
                                                    mraw, outEnh, outW);
}